// Round 5
// baseline (273.546 us; speedup 1.0000x reference)
//
#include <hip/hip_runtime.h>
#include <hip/hip_bf16.h>

// Problem constants (fixed by the reference)
#define NROWS 65536
#define DIM   512
#define H1DIM 1024
#define H2DIM 512
#define EPSC  0.15f
#define DELTA 0.05f
#define NGRP  8
#define CAPG  16384   // per-group compacted capacity (actual ~8192)

typedef __bf16 bf16x8 __attribute__((ext_vector_type(8)));
typedef float  f32x4  __attribute__((ext_vector_type(4)));

__device__ __forceinline__ void gload16(const void* g, void* lds) {
  __builtin_amdgcn_global_load_lds((__attribute__((address_space(1))) const unsigned int*)g,
                                   (__attribute__((address_space(3))) unsigned int*)lds,
                                   16, 0, 0);
}

// ---------------- zero init (y_u accumulator + group counters) ----------------
__global__ void k_zero(float* y_u, int n, int* cnt) {
  int i = blockIdx.x * blockDim.x + threadIdx.x;
  if (i < n) y_u[i] = 0.f;
  if (i < NGRP) cnt[i] = 0;
}

// ---------------- transpose + fp32->bf16 weight conversion ----------------
// src [R][C] fp32 row-major  ->  dst [C][R] bf16 row-major
__global__ void k_tcvt(const float* __restrict__ src, __bf16* __restrict__ dst, int R, int C) {
  __shared__ float tile[32][33];
  const int bi = blockIdx.x * 32;     // row base in src
  const int bj = blockIdx.y * 32;     // col base in src
  const int tx = threadIdx.x, ty = threadIdx.y;   // block (32,8)
  #pragma unroll
  for (int r = ty; r < 32; r += 8)
    tile[r][tx] = src[(size_t)(bi + r) * C + bj + tx];
  __syncthreads();
  #pragma unroll
  for (int r = ty; r < 32; r += 8)
    dst[(size_t)(bj + r) * R + bi + tx] = (__bf16)tile[tx][r];
}

// ---------------- x fp32 -> bf16 (vectorized: 2x float4 -> bf16x8) ----------------
__global__ __launch_bounds__(256) void k_cvt_x(const float4* __restrict__ x4,
                                               bf16x8* __restrict__ xb8, int n8) {
  int i = blockIdx.x * blockDim.x + threadIdx.x;
  const int stride = gridDim.x * blockDim.x;
  for (; i < n8; i += stride) {
    const float4 a = x4[2 * i];
    const float4 b = x4[2 * i + 1];
    bf16x8 v;
    v[0] = (__bf16)a.x; v[1] = (__bf16)a.y; v[2] = (__bf16)a.z; v[3] = (__bf16)a.w;
    v[4] = (__bf16)b.x; v[5] = (__bf16)b.y; v[6] = (__bf16)b.z; v[7] = (__bf16)b.w;
    xb8[i] = v;
  }
}

// ---------------- GEMM1: h1 = relu(xb @ W1 + b1), bf16 in/out ----------------
// Structural clone of GEMM2: 256x256, BK=64, 8 waves, dbuf LDS, gload_lds both sides.
// Grid 1-D: (Mc/256)*4 blocks, XCD-chunked swizzle, n-fastest.
__global__ __launch_bounds__(512, 2) void k_gemm1(const __bf16* __restrict__ xb,
                                                  const __bf16* __restrict__ w1t,
                                                  const float* __restrict__ b1,
                                                  __bf16* __restrict__ h1) {
  __shared__ __align__(16) __bf16 As[2][256 * 64];
  __shared__ __align__(16) __bf16 Bs[2][256 * 64];
  const int tid = threadIdx.x;
  const int w = tid >> 6, l = tid & 63;
  const int mt   = (int)gridDim.x >> 2;   // m-tiles (4 col-tiles)
  const int mper = mt >> 3;               // m-tiles per XCD
  const int xcd  = blockIdx.x & 7;
  const int idx  = blockIdx.x >> 3;
  const int brow = (xcd * mper + (idx >> 2)) * 256;  // chunk-local
  const int bcol = (idx & 3) * 256;
  const int lr = l & 15, lk = l >> 4;
  const int wm = w >> 2, wn = w & 3;          // 2M x 4N wave grid
  const int mbase = wm * 128, nbase = wn * 64;
  const int srow = w * 32 + (l >> 3);         // staging row (+ t*8)
  const int scol = (l & 7) * 8;               // staging col within K-tile
  const int NT = DIM / 64;                    // 8 K-steps
  f32x4 acc[8][4] = {};

  #define STAGE1(KT, BUF) do { \
    _Pragma("unroll") for (int t_ = 0; t_ < 4; ++t_) { \
      gload16(xb  + (size_t)(brow + srow + t_ * 8) * DIM + (KT) + scol, \
              As[BUF] + (w * 32 + t_ * 8) * 64); \
      gload16(w1t + (size_t)(bcol + srow + t_ * 8) * DIM + (KT) + scol, \
              Bs[BUF] + (w * 32 + t_ * 8) * 64); } } while (0)
  #define COMPUTE1(BUF) do { \
    _Pragma("unroll") for (int kk = 0; kk < 64; kk += 32) { \
      bf16x8 af[8], bq[4]; \
      _Pragma("unroll") for (int m = 0; m < 8; ++m) \
        af[m] = *(const bf16x8*)(As[BUF] + (mbase + m * 16 + lr) * 64 + kk + lk * 8); \
      _Pragma("unroll") for (int nn = 0; nn < 4; ++nn) \
        bq[nn] = *(const bf16x8*)(Bs[BUF] + (nbase + nn * 16 + lr) * 64 + kk + lk * 8); \
      __builtin_amdgcn_s_setprio(1); \
      _Pragma("unroll") for (int m = 0; m < 8; ++m) \
        _Pragma("unroll") for (int nn = 0; nn < 4; ++nn) \
          acc[m][nn] = __builtin_amdgcn_mfma_f32_16x16x32_bf16(af[m], bq[nn], acc[m][nn], 0, 0, 0); \
      __builtin_amdgcn_s_setprio(0); \
    } } while (0)

  STAGE1(0, 0);
  __syncthreads();
  int cur = 0;
  for (int t = 0; t < NT - 1; ++t) {
    STAGE1((t + 1) * 64, cur ^ 1);   // issue next-tile loads before compute
    COMPUTE1(cur);
    __syncthreads();
    cur ^= 1;
  }
  COMPUTE1(cur);

  #undef STAGE1
  #undef COMPUTE1

  // epilogue: bias + relu + bf16 store
  #pragma unroll
  for (int nn = 0; nn < 4; ++nn) {
    const int col = bcol + nbase + nn * 16 + lr;
    const float bias = b1[col];
    #pragma unroll
    for (int m = 0; m < 8; ++m) {
      const int row = brow + mbase + m * 16 + lk * 4;   // chunk-local
      #pragma unroll
      for (int j = 0; j < 4; ++j) {
        float v = acc[m][nn][j] + bias;
        v = fmaxf(v, 0.f);
        h1[(size_t)(row + j) * H1DIM + col] = (__bf16)v;
      }
    }
  }
}

// ---------------- GEMM2 fused: y_u += relu(h1 @ W2 + b2) @ Wf ----------------
// Same 256x256 / BK=64 / 8-wave / dbuf 2-phase structure; both tiles via gload_lds.
// Grid 1-D: (Mc/256)*2 blocks.
__global__ __launch_bounds__(512, 2) void k_gemm2(const __bf16* __restrict__ h1,
                                                  const __bf16* __restrict__ w2t,
                                                  const float* __restrict__ b2,
                                                  const float* __restrict__ wf,
                                                  float* __restrict__ y_u, int row0) {
  __shared__ __align__(16) __bf16 As[2][256 * 64];
  __shared__ __align__(16) __bf16 Bs[2][256 * 64];
  __shared__ float yred[256];
  const int tid = threadIdx.x;
  const int w = tid >> 6, l = tid & 63;
  const int mt   = (int)gridDim.x >> 1;   // m-tiles (2 col-tiles)
  const int mper = mt >> 3;
  const int xcd  = blockIdx.x & 7;
  const int idx  = blockIdx.x >> 3;
  const int brow = (xcd * mper + (idx >> 1)) * 256;  // chunk-local
  const int n0   = (idx & 1) * 256;
  const int lr = l & 15, lk = l >> 4;
  const int wm = w >> 2, wn = w & 3;
  const int mbase = wm * 128, nbase = wn * 64;
  const int srow = w * 32 + (l >> 3);
  const int scol = (l & 7) * 8;
  const int NT = H1DIM / 64;              // 16 K-steps
  f32x4 acc[8][4] = {};

  #define STAGE2(KT, BUF) do { \
    _Pragma("unroll") for (int t_ = 0; t_ < 4; ++t_) { \
      gload16(h1  + (size_t)(brow + srow + t_ * 8) * H1DIM + (KT) + scol, \
              As[BUF] + (w * 32 + t_ * 8) * 64); \
      gload16(w2t + (size_t)(n0   + srow + t_ * 8) * H1DIM + (KT) + scol, \
              Bs[BUF] + (w * 32 + t_ * 8) * 64); } } while (0)
  #define COMPUTE2(BUF) do { \
    _Pragma("unroll") for (int kk = 0; kk < 64; kk += 32) { \
      bf16x8 af[8], bq[4]; \
      _Pragma("unroll") for (int m = 0; m < 8; ++m) \
        af[m] = *(const bf16x8*)(As[BUF] + (mbase + m * 16 + lr) * 64 + kk + lk * 8); \
      _Pragma("unroll") for (int nn = 0; nn < 4; ++nn) \
        bq[nn] = *(const bf16x8*)(Bs[BUF] + (nbase + nn * 16 + lr) * 64 + kk + lk * 8); \
      __builtin_amdgcn_s_setprio(1); \
      _Pragma("unroll") for (int m = 0; m < 8; ++m) \
        _Pragma("unroll") for (int nn = 0; nn < 4; ++nn) \
          acc[m][nn] = __builtin_amdgcn_mfma_f32_16x16x32_bf16(af[m], bq[nn], acc[m][nn], 0, 0, 0); \
      __builtin_amdgcn_s_setprio(0); \
    } } while (0)

  STAGE2(0, 0);
  __syncthreads();
  int cur = 0;
  for (int t = 0; t < NT - 1; ++t) {
    STAGE2((t + 1) * 64, cur ^ 1);   // issue next-tile loads before compute
    COMPUTE2(cur);
    __syncthreads();
    cur ^= 1;
  }
  COMPUTE2(cur);

  #undef STAGE2
  #undef COMPUTE2

  // epilogue: relu + dot with Wf over this block's 256 h2-columns
  float yacc[8][4] = {};
  #pragma unroll
  for (int nn = 0; nn < 4; ++nn) {
    const int col = n0 + nbase + nn * 16 + lr;
    const float bias = b2[col];
    const float wfv = wf[col];
    #pragma unroll
    for (int m = 0; m < 8; ++m)
      #pragma unroll
      for (int j = 0; j < 4; ++j)
        yacc[m][j] += fmaxf(acc[m][nn][j] + bias, 0.f) * wfv;
  }
  #pragma unroll
  for (int m = 0; m < 8; ++m)
    #pragma unroll
    for (int j = 0; j < 4; ++j) {
      float v = yacc[m][j];
      v += __shfl_xor(v, 1, 64);
      v += __shfl_xor(v, 2, 64);
      v += __shfl_xor(v, 4, 64);
      v += __shfl_xor(v, 8, 64);
      yacc[m][j] = v;
    }
  if (tid < 256) yred[tid] = 0.f;
  __syncthreads();
  if (lr == 0) {
    #pragma unroll
    for (int m = 0; m < 8; ++m)
      #pragma unroll
      for (int j = 0; j < 4; ++j)
        atomicAdd(&yred[mbase + m * 16 + lk * 4 + j], yacc[m][j]);
  }
  __syncthreads();
  if (tid < 256) atomicAdd(&y_u[row0 + brow + tid], yred[tid]);
}

// ---------------- projection: scatter per-group compacted (z0, w) ----------------
__global__ __launch_bounds__(256) void k_scatter(const float* __restrict__ y_u,
                                                 const float* __restrict__ c,
                                                 const float* __restrict__ mask,
                                                 const float* __restrict__ bfp,
                                                 float* __restrict__ z0c, float* __restrict__ wc,
                                                 unsigned char* __restrict__ gidx,
                                                 int* __restrict__ cnt, int n) {
  __shared__ int lcnt[NGRP];
  __shared__ int lbase[NGRP];
  const float bf0 = bfp[0];
  const int tid = threadIdx.x;
  if (tid < NGRP) lcnt[tid] = 0;
  __syncthreads();
  const int i = blockIdx.x * blockDim.x + tid;
  int g = 0, slot_l = 0;
  float z0 = 0.f, wv = 0.f;
  if (i < n) {
    const float cv = c[i];
    z0 = (y_u[i] + bf0) / cv - 1.f;
    wv = cv * cv;
    #pragma unroll
    for (int j = 1; j < NGRP; ++j)
      if (mask[(size_t)j * NROWS + i] > 0.5f) g = j;
    slot_l = atomicAdd(&lcnt[g], 1);      // LDS atomic: cheap
    gidx[i] = (unsigned char)g;
  }
  __syncthreads();
  if (tid < NGRP) lbase[tid] = atomicAdd(&cnt[tid], lcnt[tid]);  // 8 global atomics/block
  __syncthreads();
  if (i < n) {
    const int slot = lbase[g] + slot_l;
    if (slot < CAPG) {
      z0c[(size_t)g * CAPG + slot] = z0;
      wc [(size_t)g * CAPG + slot] = wv;
    }
  }
}

// ---------------- block reductions for k_mu ----------------
__device__ __forceinline__ float wave_red(float v, int mode) {
  #pragma unroll
  for (int o = 32; o > 0; o >>= 1) {
    float u = __shfl_xor(v, o, 64);
    v = (mode == 0) ? (v + u) : ((mode == 1) ? fmaxf(v, u) : fminf(v, u));
  }
  return v;
}
__device__ __forceinline__ float block_red(float v, int mode, float* red, int tid) {
  v = wave_red(v, mode);
  if ((tid & 63) == 0) red[tid >> 6] = v;
  __syncthreads();
  if (tid < 64) {
    float x = (tid < 16) ? red[tid] : (mode == 0 ? 0.f : (mode == 1 ? -1e30f : 1e30f));
    x = wave_red(x, mode);
    if (tid == 0) red[0] = x;
  }
  __syncthreads();
  float r = red[0];
  __syncthreads();
  return r;
}

// ---------------- per-group KKT multiplier via bisection ----------------
__global__ __launch_bounds__(1024) void k_mu(const float* __restrict__ z0c,
                                             const float* __restrict__ wc,
                                             const int* __restrict__ cnt,
                                             float* __restrict__ muarr) {
  __shared__ float red[16];
  const int g = blockIdx.x;
  const int tid = threadIdx.x;
  int n = cnt[g];
  if (n > CAPG) n = CAPG;
  if (n <= 0) { if (tid == 0) muarr[g] = 0.f; return; }
  float z0v[16], iwv[16];
  float hmax = -1e30f, hmin = 1e30f;
  #pragma unroll
  for (int t = 0; t < 16; ++t) {
    const int idx = t * 1024 + tid;
    if (idx < n) {
      const float z0 = z0c[(size_t)g * CAPG + idx];
      const float wv = wc[(size_t)g * CAPG + idx];
      z0v[t] = z0; iwv[t] = 1.f / wv;
      hmax = fmaxf(hmax, (z0 + EPSC) * wv);
      hmin = fminf(hmin, (z0 - EPSC) * wv);
    } else { z0v[t] = 0.f; iwv[t] = 0.f; }
  }
  const float inv_n = 1.f / (float)n;
  #define EVALM(MU, OUT) do { float s_ = 0.f; \
    _Pragma("unroll") for (int t = 0; t < 16; ++t) \
      s_ += fminf(fmaxf(z0v[t] - (MU) * iwv[t], -EPSC), EPSC); \
    OUT = block_red(s_, 0, red, tid) * inv_n; } while (0)
  float m0; EVALM(0.f, m0);
  float mu = 0.f;
  if (fabsf(m0) > DELTA) {
    float target, lo, hi;
    if (m0 > 0.f) { target = DELTA;  lo = 0.f; hi = block_red(hmax, 1, red, tid); }
    else          { target = -DELTA; hi = 0.f; lo = block_red(hmin, 2, red, tid); }
    for (int it = 0; it < 32; ++it) {
      const float mid = 0.5f * (lo + hi);
      float mm; EVALM(mid, mm);
      if (mm >= target) lo = mid; else hi = mid;
    }
    mu = 0.5f * (lo + hi);
  }
  if (tid == 0) muarr[g] = mu;
  #undef EVALM
}

// ---------------- final: y = (clip(z0 - mu/w, +-EPS) + 1) * c ----------------
__global__ void k_y(const float* __restrict__ y_u, const float* __restrict__ c,
                    const float* __restrict__ bfp, const unsigned char* __restrict__ gidx,
                    const float* __restrict__ muarr, float* __restrict__ out, int n) {
  const float bf0 = bfp[0];
  int i = blockIdx.x * blockDim.x + threadIdx.x;
  const int stride = gridDim.x * blockDim.x;
  for (; i < n; i += stride) {
    const float cv = c[i];
    const float z0 = (y_u[i] + bf0) / cv - 1.f;
    const float wv = cv * cv;
    const float mu = muarr[gidx[i]];
    const float z = fminf(fmaxf(z0 - mu / wv, -EPSC), EPSC);
    out[i] = (z + 1.f) * cv;
  }
}

extern "C" void kernel_launch(void* const* d_in, const int* in_sizes, int n_in,
                              void* d_out, int out_size, void* d_ws, size_t ws_size,
                              hipStream_t stream) {
  const float* x    = (const float*)d_in[0];
  const float* W1   = (const float*)d_in[1];
  const float* b1   = (const float*)d_in[2];
  const float* W2   = (const float*)d_in[3];
  const float* b2   = (const float*)d_in[4];
  const float* Wf   = (const float*)d_in[5];
  const float* bfp  = (const float*)d_in[6];
  const float* c    = (const float*)d_in[7];
  const float* mask = (const float*)d_in[8];
  float* out = (float*)d_out;

  char* ws = (char*)d_ws;
  size_t off = 0;
  auto alloc = [&](size_t bytes) -> void* {
    void* p = ws + off;
    off += (bytes + 255) & ~(size_t)255;
    return p;
  };
  __bf16* w1t = (__bf16*)alloc((size_t)H1DIM * DIM * 2);
  __bf16* w2t = (__bf16*)alloc((size_t)H2DIM * H1DIM * 2);
  float* y_u  = (float*)alloc((size_t)NROWS * 4);
  float* z0c  = (float*)alloc((size_t)NGRP * CAPG * 4);
  float* wc   = (float*)alloc((size_t)NGRP * CAPG * 4);
  unsigned char* gidx = (unsigned char*)alloc(NROWS);
  int*   cnt  = (int*)alloc(NGRP * 4);
  float* muarr = (float*)alloc(NGRP * 4);
  const size_t fixed = off;

  // per-chunk buffers: xb (1 KB/row) + h1 (2 KB/row) -> 3 KB/row.
  // Chunk must be a multiple of 2048 rows (256-row tiles, m-tiles % 8 == 0).
  size_t avail = (ws_size > fixed) ? (ws_size - fixed) : 0;
  long long rc = (long long)(avail / ((size_t)(DIM + H1DIM * 2)));
  rc &= ~2047LL;
  if (rc > 32768) rc = 32768;
  if (rc < 2048) rc = 2048;   // below this ws is insufficient; assume harness gives enough
  const int rows_chunk = (int)rc;
  __bf16* xb = (__bf16*)(ws + fixed);
  __bf16* h1 = (__bf16*)(ws + fixed + (size_t)rows_chunk * DIM * 2);

  k_zero<<<dim3((NROWS + 255) / 256), dim3(256), 0, stream>>>(y_u, NROWS, cnt);
  k_tcvt<<<dim3(DIM / 32, H1DIM / 32), dim3(32, 8), 0, stream>>>(W1, w1t, DIM, H1DIM);
  k_tcvt<<<dim3(H1DIM / 32, H2DIM / 32), dim3(32, 8), 0, stream>>>(W2, w2t, H1DIM, H2DIM);

  for (int r0 = 0; r0 < NROWS; r0 += rows_chunk) {
    const int Mc = (NROWS - r0 < rows_chunk) ? (NROWS - r0) : rows_chunk;
    const int mtiles = Mc / 256;
    const int n8 = Mc * (DIM / 8);
    int cblocks = (n8 + 255) / 256; if (cblocks > 2048) cblocks = 2048;
    k_cvt_x<<<dim3(cblocks), dim3(256), 0, stream>>>(
        (const float4*)(x + (size_t)r0 * DIM), (bf16x8*)xb, n8);
    k_gemm1<<<dim3(mtiles * 4), dim3(512), 0, stream>>>(xb, w1t, b1, h1);
    k_gemm2<<<dim3(mtiles * 2), dim3(512), 0, stream>>>(h1, w2t, b2, Wf, y_u, r0);
  }

  k_scatter<<<dim3((NROWS + 255) / 256), dim3(256), 0, stream>>>(y_u, c, mask, bfp, z0c, wc, gidx, cnt, NROWS);
  k_mu<<<dim3(NGRP), dim3(1024), 0, stream>>>(z0c, wc, cnt, muarr);
  k_y<<<dim3(256), dim3(256), 0, stream>>>(y_u, c, bfp, gidx, muarr, out, NROWS);
}

// Round 6
// 241.962 us; speedup vs baseline: 1.1305x; 1.1305x over previous
//
#include <hip/hip_runtime.h>
#include <hip/hip_bf16.h>

// Problem constants (fixed by the reference)
#define NROWS 65536
#define DIM   512
#define H1DIM 1024
#define H2DIM 512
#define EPSC  0.15f
#define DELTA 0.05f
#define NGRP  8
#define CAPG  16384   // per-group compacted capacity (actual ~8192)

typedef __bf16 bf16x8 __attribute__((ext_vector_type(8)));
typedef float  f32x4  __attribute__((ext_vector_type(4)));

__device__ __forceinline__ void gload16(const void* g, void* lds) {
  __builtin_amdgcn_global_load_lds((__attribute__((address_space(1))) const unsigned int*)g,
                                   (__attribute__((address_space(3))) unsigned int*)lds,
                                   16, 0, 0);
}

// ---------------- zero init (y_u accumulator + group counters) ----------------
__global__ void k_zero(float* y_u, int n, int* cnt) {
  int i = blockIdx.x * blockDim.x + threadIdx.x;
  if (i < n) y_u[i] = 0.f;
  if (i < NGRP) cnt[i] = 0;
}

// ---------------- transpose + fp32->bf16 weight conversion ----------------
// src [R][C] fp32 row-major  ->  dst [C][R] bf16 row-major
__global__ void k_tcvt(const float* __restrict__ src, __bf16* __restrict__ dst, int R, int C) {
  __shared__ float tile[32][33];
  const int bi = blockIdx.x * 32;     // row base in src
  const int bj = blockIdx.y * 32;     // col base in src
  const int tx = threadIdx.x, ty = threadIdx.y;   // block (32,8)
  #pragma unroll
  for (int r = ty; r < 32; r += 8)
    tile[r][tx] = src[(size_t)(bi + r) * C + bj + tx];
  __syncthreads();
  #pragma unroll
  for (int r = ty; r < 32; r += 8)
    dst[(size_t)(bj + r) * R + bi + tx] = (__bf16)tile[tx][r];
}

// ---------------- x fp32 -> bf16 (vectorized: 2x float4 -> bf16x8) ----------------
__global__ __launch_bounds__(256) void k_cvt_x(const float4* __restrict__ x4,
                                               bf16x8* __restrict__ xb8, int n8) {
  int i = blockIdx.x * blockDim.x + threadIdx.x;
  const int stride = gridDim.x * blockDim.x;
  for (; i < n8; i += stride) {
    const float4 a = x4[2 * i];
    const float4 b = x4[2 * i + 1];
    bf16x8 v;
    v[0] = (__bf16)a.x; v[1] = (__bf16)a.y; v[2] = (__bf16)a.z; v[3] = (__bf16)a.w;
    v[4] = (__bf16)b.x; v[5] = (__bf16)b.y; v[6] = (__bf16)b.z; v[7] = (__bf16)b.w;
    xb8[i] = v;
  }
}

// ============ 256x256 / BK=64 / 8-wave dbuf GEMM with T4 counted-vmcnt + T2 swizzle ============
// LDS layout: linear dest for global_load_lds; source column pre-swizzled by
// slot' = (l&7) ^ ((l>>3)&7)  (row&7 == (l>>3)&7 for the staged rows);
// reads XOR byte offset with (lr&7)<<4 (read rows are lr mod 8). Rule #21 both-sides form.

// ---------------- GEMM1: h1 = relu(xb @ W1 + b1), bf16 in/out ----------------
// Grid 1-D: (Mc/256)*4 blocks, XCD-chunked swizzle, n-fastest.
__global__ __launch_bounds__(512, 2) void k_gemm1(const __bf16* __restrict__ xb,
                                                  const __bf16* __restrict__ w1t,
                                                  const float* __restrict__ b1,
                                                  __bf16* __restrict__ h1) {
  __shared__ __align__(16) __bf16 As[2][256 * 64];
  __shared__ __align__(16) __bf16 Bs[2][256 * 64];
  const int tid = threadIdx.x;
  const int w = tid >> 6, l = tid & 63;
  const int mt   = (int)gridDim.x >> 2;   // m-tiles (4 col-tiles)
  const int mper = mt >> 3;               // m-tiles per XCD
  const int xcd  = blockIdx.x & 7;
  const int idx  = blockIdx.x >> 3;
  const int brow = (xcd * mper + (idx >> 2)) * 256;  // chunk-local
  const int bcol = (idx & 3) * 256;
  const int lr = l & 15, lk = l >> 4;
  const int wm = w >> 2, wn = w & 3;          // 2M x 4N wave grid
  const int mbase = wm * 128, nbase = wn * 64;
  const int srow = w * 32 + (l >> 3);         // staging row (+ t*8)
  const int scol = (((l & 7) ^ ((l >> 3) & 7)) * 8);  // T2 inverse-swizzled source col
  const int swz  = (lr & 7) << 4;             // T2 read swizzle (byte XOR)
  const int NT = DIM / 64;                    // 8 K-steps
  f32x4 acc[8][4] = {};

  #define STAGE1(KT, BUF) do { \
    _Pragma("unroll") for (int t_ = 0; t_ < 4; ++t_) { \
      gload16(xb  + (size_t)(brow + srow + t_ * 8) * DIM + (KT) + scol, \
              As[BUF] + (w * 32 + t_ * 8) * 64); \
      gload16(w1t + (size_t)(bcol + srow + t_ * 8) * DIM + (KT) + scol, \
              Bs[BUF] + (w * 32 + t_ * 8) * 64); } } while (0)
  #define COMPUTE1(BUF) do { \
    _Pragma("unroll") for (int kk = 0; kk < 64; kk += 32) { \
      bf16x8 af[8], bq[4]; \
      _Pragma("unroll") for (int m = 0; m < 8; ++m) \
        af[m] = *(const bf16x8*)((const char*)(As[BUF]) + \
                 ((((mbase + m * 16 + lr) * 128) + kk * 2 + lk * 16) ^ swz)); \
      _Pragma("unroll") for (int nn = 0; nn < 4; ++nn) \
        bq[nn] = *(const bf16x8*)((const char*)(Bs[BUF]) + \
                 ((((nbase + nn * 16 + lr) * 128) + kk * 2 + lk * 16) ^ swz)); \
      __builtin_amdgcn_s_setprio(1); \
      _Pragma("unroll") for (int m = 0; m < 8; ++m) \
        _Pragma("unroll") for (int nn = 0; nn < 4; ++nn) \
          acc[m][nn] = __builtin_amdgcn_mfma_f32_16x16x32_bf16(af[m], bq[nn], acc[m][nn], 0, 0, 0); \
      __builtin_amdgcn_s_setprio(0); \
    } } while (0)

  STAGE1(0, 0);
  int cur = 0;
  for (int t = 0; t < NT - 1; ++t) {
    STAGE1((t + 1) * 64, cur ^ 1);                      // 8 loads stay in flight
    asm volatile("s_waitcnt vmcnt(8)" ::: "memory");    // tile t (oldest 8) done
    __builtin_amdgcn_s_barrier();                       // ready-barrier
    COMPUTE1(cur);
    __builtin_amdgcn_s_barrier();                       // free-barrier (buf[cur] reads done)
    cur ^= 1;
  }
  asm volatile("s_waitcnt vmcnt(0)" ::: "memory");
  __builtin_amdgcn_s_barrier();
  COMPUTE1(cur);

  #undef STAGE1
  #undef COMPUTE1

  // epilogue: bias + relu + bf16 store
  #pragma unroll
  for (int nn = 0; nn < 4; ++nn) {
    const int col = bcol + nbase + nn * 16 + lr;
    const float bias = b1[col];
    #pragma unroll
    for (int m = 0; m < 8; ++m) {
      const int row = brow + mbase + m * 16 + lk * 4;   // chunk-local
      #pragma unroll
      for (int j = 0; j < 4; ++j) {
        float v = acc[m][nn][j] + bias;
        v = fmaxf(v, 0.f);
        h1[(size_t)(row + j) * H1DIM + col] = (__bf16)v;
      }
    }
  }
}

// ---------------- GEMM2 fused: y_u += relu(h1 @ W2 + b2) @ Wf ----------------
// Same structure. Grid 1-D: (Mc/256)*2 blocks.
__global__ __launch_bounds__(512, 2) void k_gemm2(const __bf16* __restrict__ h1,
                                                  const __bf16* __restrict__ w2t,
                                                  const float* __restrict__ b2,
                                                  const float* __restrict__ wf,
                                                  float* __restrict__ y_u, int row0) {
  __shared__ __align__(16) __bf16 As[2][256 * 64];
  __shared__ __align__(16) __bf16 Bs[2][256 * 64];
  __shared__ float yred[256];
  const int tid = threadIdx.x;
  const int w = tid >> 6, l = tid & 63;
  const int mt   = (int)gridDim.x >> 1;   // m-tiles (2 col-tiles)
  const int mper = mt >> 3;
  const int xcd  = blockIdx.x & 7;
  const int idx  = blockIdx.x >> 3;
  const int brow = (xcd * mper + (idx >> 1)) * 256;  // chunk-local
  const int n0   = (idx & 1) * 256;
  const int lr = l & 15, lk = l >> 4;
  const int wm = w >> 2, wn = w & 3;
  const int mbase = wm * 128, nbase = wn * 64;
  const int srow = w * 32 + (l >> 3);
  const int scol = (((l & 7) ^ ((l >> 3) & 7)) * 8);  // T2 inverse-swizzled source col
  const int swz  = (lr & 7) << 4;                     // T2 read swizzle
  const int NT = H1DIM / 64;              // 16 K-steps
  f32x4 acc[8][4] = {};

  #define STAGE2(KT, BUF) do { \
    _Pragma("unroll") for (int t_ = 0; t_ < 4; ++t_) { \
      gload16(h1  + (size_t)(brow + srow + t_ * 8) * H1DIM + (KT) + scol, \
              As[BUF] + (w * 32 + t_ * 8) * 64); \
      gload16(w2t + (size_t)(n0   + srow + t_ * 8) * H1DIM + (KT) + scol, \
              Bs[BUF] + (w * 32 + t_ * 8) * 64); } } while (0)
  #define COMPUTE2(BUF) do { \
    _Pragma("unroll") for (int kk = 0; kk < 64; kk += 32) { \
      bf16x8 af[8], bq[4]; \
      _Pragma("unroll") for (int m = 0; m < 8; ++m) \
        af[m] = *(const bf16x8*)((const char*)(As[BUF]) + \
                 ((((mbase + m * 16 + lr) * 128) + kk * 2 + lk * 16) ^ swz)); \
      _Pragma("unroll") for (int nn = 0; nn < 4; ++nn) \
        bq[nn] = *(const bf16x8*)((const char*)(Bs[BUF]) + \
                 ((((nbase + nn * 16 + lr) * 128) + kk * 2 + lk * 16) ^ swz)); \
      __builtin_amdgcn_s_setprio(1); \
      _Pragma("unroll") for (int m = 0; m < 8; ++m) \
        _Pragma("unroll") for (int nn = 0; nn < 4; ++nn) \
          acc[m][nn] = __builtin_amdgcn_mfma_f32_16x16x32_bf16(af[m], bq[nn], acc[m][nn], 0, 0, 0); \
      __builtin_amdgcn_s_setprio(0); \
    } } while (0)

  STAGE2(0, 0);
  int cur = 0;
  for (int t = 0; t < NT - 1; ++t) {
    STAGE2((t + 1) * 64, cur ^ 1);
    asm volatile("s_waitcnt vmcnt(8)" ::: "memory");
    __builtin_amdgcn_s_barrier();
    COMPUTE2(cur);
    __builtin_amdgcn_s_barrier();
    cur ^= 1;
  }
  asm volatile("s_waitcnt vmcnt(0)" ::: "memory");
  __builtin_amdgcn_s_barrier();
  COMPUTE2(cur);

  #undef STAGE2
  #undef COMPUTE2

  // epilogue: relu + dot with Wf over this block's 256 h2-columns
  float yacc[8][4] = {};
  #pragma unroll
  for (int nn = 0; nn < 4; ++nn) {
    const int col = n0 + nbase + nn * 16 + lr;
    const float bias = b2[col];
    const float wfv = wf[col];
    #pragma unroll
    for (int m = 0; m < 8; ++m)
      #pragma unroll
      for (int j = 0; j < 4; ++j)
        yacc[m][j] += fmaxf(acc[m][nn][j] + bias, 0.f) * wfv;
  }
  #pragma unroll
  for (int m = 0; m < 8; ++m)
    #pragma unroll
    for (int j = 0; j < 4; ++j) {
      float v = yacc[m][j];
      v += __shfl_xor(v, 1, 64);
      v += __shfl_xor(v, 2, 64);
      v += __shfl_xor(v, 4, 64);
      v += __shfl_xor(v, 8, 64);
      yacc[m][j] = v;
    }
  if (tid < 256) yred[tid] = 0.f;
  __syncthreads();
  if (lr == 0) {
    #pragma unroll
    for (int m = 0; m < 8; ++m)
      #pragma unroll
      for (int j = 0; j < 4; ++j)
        atomicAdd(&yred[mbase + m * 16 + lk * 4 + j], yacc[m][j]);
  }
  __syncthreads();
  if (tid < 256) atomicAdd(&y_u[row0 + brow + tid], yred[tid]);
}

// ---------------- projection: scatter per-group compacted (z0, w) ----------------
__global__ __launch_bounds__(256) void k_scatter(const float* __restrict__ y_u,
                                                 const float* __restrict__ c,
                                                 const float* __restrict__ mask,
                                                 const float* __restrict__ bfp,
                                                 float* __restrict__ z0c, float* __restrict__ wc,
                                                 unsigned char* __restrict__ gidx,
                                                 int* __restrict__ cnt, int n) {
  __shared__ int lcnt[NGRP];
  __shared__ int lbase[NGRP];
  const float bf0 = bfp[0];
  const int tid = threadIdx.x;
  if (tid < NGRP) lcnt[tid] = 0;
  __syncthreads();
  const int i = blockIdx.x * blockDim.x + tid;
  int g = 0, slot_l = 0;
  float z0 = 0.f, wv = 0.f;
  if (i < n) {
    const float cv = c[i];
    z0 = (y_u[i] + bf0) / cv - 1.f;
    wv = cv * cv;
    #pragma unroll
    for (int j = 1; j < NGRP; ++j)
      if (mask[(size_t)j * NROWS + i] > 0.5f) g = j;
    slot_l = atomicAdd(&lcnt[g], 1);      // LDS atomic: cheap
    gidx[i] = (unsigned char)g;
  }
  __syncthreads();
  if (tid < NGRP) lbase[tid] = atomicAdd(&cnt[tid], lcnt[tid]);  // 8 global atomics/block
  __syncthreads();
  if (i < n) {
    const int slot = lbase[g] + slot_l;
    if (slot < CAPG) {
      z0c[(size_t)g * CAPG + slot] = z0;
      wc [(size_t)g * CAPG + slot] = wv;
    }
  }
}

// ---------------- block reductions for k_mu ----------------
__device__ __forceinline__ float wave_red(float v, int mode) {
  #pragma unroll
  for (int o = 32; o > 0; o >>= 1) {
    float u = __shfl_xor(v, o, 64);
    v = (mode == 0) ? (v + u) : ((mode == 1) ? fmaxf(v, u) : fminf(v, u));
  }
  return v;
}
__device__ __forceinline__ float block_red(float v, int mode, float* red, int tid) {
  v = wave_red(v, mode);
  if ((tid & 63) == 0) red[tid >> 6] = v;
  __syncthreads();
  if (tid < 64) {
    float x = (tid < 16) ? red[tid] : (mode == 0 ? 0.f : (mode == 1 ? -1e30f : 1e30f));
    x = wave_red(x, mode);
    if (tid == 0) red[0] = x;
  }
  __syncthreads();
  float r = red[0];
  __syncthreads();
  return r;
}

// ---------------- per-group KKT multiplier via bisection ----------------
__global__ __launch_bounds__(1024) void k_mu(const float* __restrict__ z0c,
                                             const float* __restrict__ wc,
                                             const int* __restrict__ cnt,
                                             float* __restrict__ muarr) {
  __shared__ float red[16];
  const int g = blockIdx.x;
  const int tid = threadIdx.x;
  int n = cnt[g];
  if (n > CAPG) n = CAPG;
  if (n <= 0) { if (tid == 0) muarr[g] = 0.f; return; }
  float z0v[16], iwv[16];
  float hmax = -1e30f, hmin = 1e30f;
  #pragma unroll
  for (int t = 0; t < 16; ++t) {
    const int idx = t * 1024 + tid;
    if (idx < n) {
      const float z0 = z0c[(size_t)g * CAPG + idx];
      const float wv = wc[(size_t)g * CAPG + idx];
      z0v[t] = z0; iwv[t] = 1.f / wv;
      hmax = fmaxf(hmax, (z0 + EPSC) * wv);
      hmin = fminf(hmin, (z0 - EPSC) * wv);
    } else { z0v[t] = 0.f; iwv[t] = 0.f; }
  }
  const float inv_n = 1.f / (float)n;
  #define EVALM(MU, OUT) do { float s_ = 0.f; \
    _Pragma("unroll") for (int t = 0; t < 16; ++t) \
      s_ += fminf(fmaxf(z0v[t] - (MU) * iwv[t], -EPSC), EPSC); \
    OUT = block_red(s_, 0, red, tid) * inv_n; } while (0)
  float m0; EVALM(0.f, m0);
  float mu = 0.f;
  if (fabsf(m0) > DELTA) {
    float target, lo, hi;
    if (m0 > 0.f) { target = DELTA;  lo = 0.f; hi = block_red(hmax, 1, red, tid); }
    else          { target = -DELTA; hi = 0.f; lo = block_red(hmin, 2, red, tid); }
    for (int it = 0; it < 32; ++it) {
      const float mid = 0.5f * (lo + hi);
      float mm; EVALM(mid, mm);
      if (mm >= target) lo = mid; else hi = mid;
    }
    mu = 0.5f * (lo + hi);
  }
  if (tid == 0) muarr[g] = mu;
  #undef EVALM
}

// ---------------- final: y = (clip(z0 - mu/w, +-EPS) + 1) * c ----------------
__global__ void k_y(const float* __restrict__ y_u, const float* __restrict__ c,
                    const float* __restrict__ bfp, const unsigned char* __restrict__ gidx,
                    const float* __restrict__ muarr, float* __restrict__ out, int n) {
  const float bf0 = bfp[0];
  int i = blockIdx.x * blockDim.x + threadIdx.x;
  const int stride = gridDim.x * blockDim.x;
  for (; i < n; i += stride) {
    const float cv = c[i];
    const float z0 = (y_u[i] + bf0) / cv - 1.f;
    const float wv = cv * cv;
    const float mu = muarr[gidx[i]];
    const float z = fminf(fmaxf(z0 - mu / wv, -EPSC), EPSC);
    out[i] = (z + 1.f) * cv;
  }
}

extern "C" void kernel_launch(void* const* d_in, const int* in_sizes, int n_in,
                              void* d_out, int out_size, void* d_ws, size_t ws_size,
                              hipStream_t stream) {
  const float* x    = (const float*)d_in[0];
  const float* W1   = (const float*)d_in[1];
  const float* b1   = (const float*)d_in[2];
  const float* W2   = (const float*)d_in[3];
  const float* b2   = (const float*)d_in[4];
  const float* Wf   = (const float*)d_in[5];
  const float* bfp  = (const float*)d_in[6];
  const float* c    = (const float*)d_in[7];
  const float* mask = (const float*)d_in[8];
  float* out = (float*)d_out;

  char* ws = (char*)d_ws;
  size_t off = 0;
  auto alloc = [&](size_t bytes) -> void* {
    void* p = ws + off;
    off += (bytes + 255) & ~(size_t)255;
    return p;
  };
  __bf16* w1t = (__bf16*)alloc((size_t)H1DIM * DIM * 2);
  __bf16* w2t = (__bf16*)alloc((size_t)H2DIM * H1DIM * 2);
  float* y_u  = (float*)alloc((size_t)NROWS * 4);
  float* z0c  = (float*)alloc((size_t)NGRP * CAPG * 4);
  float* wc   = (float*)alloc((size_t)NGRP * CAPG * 4);
  unsigned char* gidx = (unsigned char*)alloc(NROWS);
  int*   cnt  = (int*)alloc(NGRP * 4);
  float* muarr = (float*)alloc(NGRP * 4);
  const size_t fixed = off;

  // per-chunk buffers: xb (1 KB/row) + h1 (2 KB/row) -> 3 KB/row.
  // Chunk must be a multiple of 2048 rows (256-row tiles, m-tiles % 8 == 0).
  size_t avail = (ws_size > fixed) ? (ws_size - fixed) : 0;
  long long rc = (long long)(avail / ((size_t)(DIM + H1DIM * 2)));
  rc &= ~2047LL;
  if (rc > 32768) rc = 32768;
  if (rc < 2048) rc = 2048;   // below this ws is insufficient; assume harness gives enough
  const int rows_chunk = (int)rc;
  __bf16* xb = (__bf16*)(ws + fixed);
  __bf16* h1 = (__bf16*)(ws + fixed + (size_t)rows_chunk * DIM * 2);

  k_zero<<<dim3((NROWS + 255) / 256), dim3(256), 0, stream>>>(y_u, NROWS, cnt);
  k_tcvt<<<dim3(DIM / 32, H1DIM / 32), dim3(32, 8), 0, stream>>>(W1, w1t, DIM, H1DIM);
  k_tcvt<<<dim3(H1DIM / 32, H2DIM / 32), dim3(32, 8), 0, stream>>>(W2, w2t, H1DIM, H2DIM);

  for (int r0 = 0; r0 < NROWS; r0 += rows_chunk) {
    const int Mc = (NROWS - r0 < rows_chunk) ? (NROWS - r0) : rows_chunk;
    const int mtiles = Mc / 256;
    const int n8 = Mc * (DIM / 8);
    int cblocks = (n8 + 255) / 256; if (cblocks > 2048) cblocks = 2048;
    k_cvt_x<<<dim3(cblocks), dim3(256), 0, stream>>>(
        (const float4*)(x + (size_t)r0 * DIM), (bf16x8*)xb, n8);
    k_gemm1<<<dim3(mtiles * 4), dim3(512), 0, stream>>>(xb, w1t, b1, h1);
    k_gemm2<<<dim3(mtiles * 2), dim3(512), 0, stream>>>(h1, w2t, b2, Wf, y_u, r0);
  }

  k_scatter<<<dim3((NROWS + 255) / 256), dim3(256), 0, stream>>>(y_u, c, mask, bfp, z0c, wc, gidx, cnt, NROWS);
  k_mu<<<dim3(NGRP), dim3(1024), 0, stream>>>(z0c, wc, cnt, muarr);
  k_y<<<dim3(256), dim3(256), 0, stream>>>(y_u, c, bfp, gidx, muarr, out, NROWS);
}